// Round 1
// baseline (18084.288 us; speedup 1.0000x reference)
//
#include <hip/hip_runtime.h>
#include <hip/hip_bf16.h>
#include <math.h>

#define BATCH 128
#define NN 512
#define DD 128
#define HH 8
#define DH 16
#define D3 384
#define NEGV (-1.0e9f)

// ---------------- fixed context: graph_embed = mean_n emb; fixed = ge @ Wf ----
__global__ __launch_bounds__(256) void k_fixed(const float* __restrict__ emb,
                                               const float* __restrict__ Wf,
                                               float* __restrict__ fixedc) {
  const int b = blockIdx.x;
  __shared__ float s_part[2][DD];
  __shared__ float s_ge[DD];
  const int tid = threadIdx.x;
  const int d = tid & 127, c = tid >> 7;  // c in {0,1}
  const float* e = emb + (size_t)b * NN * DD;
  float acc = 0.f;
  for (int n = c * 256; n < c * 256 + 256; ++n) acc += e[(size_t)n * DD + d];
  s_part[c][d] = acc;
  __syncthreads();
  if (tid < DD) s_ge[tid] = (s_part[0][tid] + s_part[1][tid]) * (1.0f / 512.0f);
  __syncthreads();
  if (tid < DD) {
    float a = 0.f;
    for (int k = 0; k < DD; ++k) a += s_ge[k] * Wf[k * DD + tid];
    fixedc[b * DD + tid] = a;
  }
}

// ---------------- proj = emb @ W_node_proj : [B*N,128] x [128,384] ------------
__global__ __launch_bounds__(384) void k_proj(const float* __restrict__ emb,
                                              const float* __restrict__ Wp,
                                              float* __restrict__ proj) {
  const size_t row0 = (size_t)blockIdx.x * 32;  // 2048 blocks x 32 rows
  __shared__ float s_A[32][DD];
  const int tid = threadIdx.x;  // 384
  for (int t = tid; t < 32 * DD; t += 384)
    s_A[t >> 7][t & 127] = emb[row0 * DD + t];
  __syncthreads();
  float acc[32];
#pragma unroll
  for (int r = 0; r < 32; ++r) acc[r] = 0.f;
  const int c = tid;
  for (int k = 0; k < DD; ++k) {
    float w = Wp[k * D3 + c];
    float a = s_A[0][k];  // compiler keeps these as broadcasts
#pragma unroll
    for (int r = 0; r < 32; ++r) acc[r] += s_A[r][k] * w;
    (void)a;
  }
  for (int r = 0; r < 32; ++r) proj[(row0 + r) * D3 + c] = acc[r];
}

// ---------------- persistent greedy decode: one block per batch ---------------
__global__ __launch_bounds__(1024) void k_decode(
    const float* __restrict__ emb, const float* __restrict__ proj,
    const float* __restrict__ fixedc, const float* __restrict__ Wstep,
    const float* __restrict__ Wout, const float* __restrict__ Wph,
    float* __restrict__ out) {
  const int b = blockIdx.x;
  const int tid = threadIdx.x;
  const int lane = tid & 63;
  const int wave = tid >> 6;

  __shared__ float s_ctx[2 * DD];
  __shared__ float s_q[DD];
  __shared__ float s_part[8][DD];
  __shared__ float s_compat[8 * 516];  // pitch 516 to break bank conflicts
  __shared__ float s_hp[16][17];
  __shared__ float s_wmax[16];
  __shared__ float s_wsum[16];
  __shared__ float s_heads[DD];
  __shared__ float s_glimpse[DD];
  __shared__ float s_logits[NN];
  __shared__ unsigned char s_visited[NN];
  __shared__ float s_rm[8];
  __shared__ int s_ri[8];
  __shared__ float s_es[8];
  __shared__ int s_sel, s_first, s_prev;
  __shared__ float s_m, s_logZ, s_ll;

  const float inv_sqrt_dh = 0.25f;                   // 1/sqrt(16)
  const float inv_sqrt_d = 0.08838834764831845f;     // 1/sqrt(128)
  const size_t eb = (size_t)b * NN * DD;
  const float* projb = proj + (size_t)b * NN * D3;
  float* outp = out + (size_t)b * NN * NN;
  const size_t PI_OFF = (size_t)BATCH * NN * NN;
  const size_t LL_OFF = PI_OFF + (size_t)BATCH * NN;

  if (tid < NN) s_visited[tid] = 0;
  if (tid == 0) { s_first = 0; s_prev = 0; s_ll = 0.f; }
  __syncthreads();

  for (int i = 0; i < NN; ++i) {
    // ---- A: step context (placeholder at i==0, else concat(emb[first],emb[prev]))
    if (tid < 2 * DD) {
      float v;
      if (i == 0) {
        v = Wph[tid];
      } else {
        v = (tid < DD) ? emb[eb + (size_t)s_first * DD + tid]
                       : emb[eb + (size_t)s_prev * DD + (tid - DD)];
      }
      s_ctx[tid] = v;
    }
    __syncthreads();

    // ---- B: q = fixed_ctx + ctx @ Wstep  (8 k-chunks of 32)
    {
      const int d = tid & 127, c = tid >> 7;
      float a = 0.f;
      const int k0 = c * 32;
      for (int k = k0; k < k0 + 32; ++k) a += s_ctx[k] * Wstep[k * DD + d];
      s_part[c][d] = a;
    }
    __syncthreads();
    if (tid < DD) {
      float a = fixedc[b * DD + tid];
#pragma unroll
      for (int c2 = 0; c2 < 8; ++c2) a += s_part[c2][tid];
      s_q[tid] = a;
    }
    __syncthreads();

    // ---- C: compat[h][n] = q_h . gK[n,h] * inv_sqrt_dh (masked)
    {
      const int h = tid & 7;
      float qf[16];
#pragma unroll
      for (int d = 0; d < 16; ++d) qf[d] = s_q[h * 16 + d];
#pragma unroll
      for (int j = 0; j < 4; ++j) {
        const int n = (tid >> 3) + j * 128;
        const float4* kp =
            (const float4*)(projb + (size_t)n * D3 + h * 16);
        float acc = 0.f;
#pragma unroll
        for (int v4 = 0; v4 < 4; ++v4) {
          float4 kv = kp[v4];
          acc += qf[v4 * 4 + 0] * kv.x + qf[v4 * 4 + 1] * kv.y +
                 qf[v4 * 4 + 2] * kv.z + qf[v4 * 4 + 3] * kv.w;
        }
        float cv = acc * inv_sqrt_dh;
        if (s_visited[n]) cv = NEGV;
        s_compat[h * 516 + n] = cv;
      }
    }
    __syncthreads();

    // ---- D: per-head masked softmax + heads = attn @ gV
    {
      const int h = wave & 7, nh = wave >> 3;
      const int nbase = nh * 256;
      float cv[4];
#pragma unroll
      for (int k = 0; k < 4; ++k)
        cv[k] = s_compat[h * 516 + nbase + k * 64 + lane];
      float m = fmaxf(fmaxf(cv[0], cv[1]), fmaxf(cv[2], cv[3]));
#pragma unroll
      for (int off = 32; off >= 1; off >>= 1) m = fmaxf(m, __shfl_xor(m, off));
      if (lane == 0) s_wmax[wave] = m;
      __syncthreads();
      m = fmaxf(s_wmax[h], s_wmax[h + 8]);
      float p[4];
      float sum = 0.f;
#pragma unroll
      for (int k = 0; k < 4; ++k) {
        p[k] = expf(cv[k] - m);  // masked -> exp(-1e9-m) = 0
        sum += p[k];
      }
#pragma unroll
      for (int off = 32; off >= 1; off >>= 1) sum += __shfl_xor(sum, off);
      float acc0 = 0.f, acc1 = 0.f, acc2 = 0.f, acc3 = 0.f, acc4 = 0.f,
            acc5 = 0.f, acc6 = 0.f, acc7 = 0.f, acc8 = 0.f, acc9 = 0.f,
            acc10 = 0.f, acc11 = 0.f, acc12 = 0.f, acc13 = 0.f, acc14 = 0.f,
            acc15 = 0.f;
#pragma unroll
      for (int k = 0; k < 4; ++k) {
        const int n = nbase + k * 64 + lane;
        const float4* vp =
            (const float4*)(projb + (size_t)n * D3 + DD + h * 16);
        float4 v0 = vp[0], v1 = vp[1], v2 = vp[2], v3 = vp[3];
        const float pk = p[k];
        acc0 += pk * v0.x; acc1 += pk * v0.y; acc2 += pk * v0.z; acc3 += pk * v0.w;
        acc4 += pk * v1.x; acc5 += pk * v1.y; acc6 += pk * v1.z; acc7 += pk * v1.w;
        acc8 += pk * v2.x; acc9 += pk * v2.y; acc10 += pk * v2.z; acc11 += pk * v2.w;
        acc12 += pk * v3.x; acc13 += pk * v3.y; acc14 += pk * v3.z; acc15 += pk * v3.w;
      }
#pragma unroll
      for (int off = 32; off >= 1; off >>= 1) {
        acc0 += __shfl_xor(acc0, off);   acc1 += __shfl_xor(acc1, off);
        acc2 += __shfl_xor(acc2, off);   acc3 += __shfl_xor(acc3, off);
        acc4 += __shfl_xor(acc4, off);   acc5 += __shfl_xor(acc5, off);
        acc6 += __shfl_xor(acc6, off);   acc7 += __shfl_xor(acc7, off);
        acc8 += __shfl_xor(acc8, off);   acc9 += __shfl_xor(acc9, off);
        acc10 += __shfl_xor(acc10, off); acc11 += __shfl_xor(acc11, off);
        acc12 += __shfl_xor(acc12, off); acc13 += __shfl_xor(acc13, off);
        acc14 += __shfl_xor(acc14, off); acc15 += __shfl_xor(acc15, off);
      }
      if (lane == 0) {
        s_wsum[wave] = sum;
        s_hp[wave][0] = acc0;   s_hp[wave][1] = acc1;
        s_hp[wave][2] = acc2;   s_hp[wave][3] = acc3;
        s_hp[wave][4] = acc4;   s_hp[wave][5] = acc5;
        s_hp[wave][6] = acc6;   s_hp[wave][7] = acc7;
        s_hp[wave][8] = acc8;   s_hp[wave][9] = acc9;
        s_hp[wave][10] = acc10; s_hp[wave][11] = acc11;
        s_hp[wave][12] = acc12; s_hp[wave][13] = acc13;
        s_hp[wave][14] = acc14; s_hp[wave][15] = acc15;
      }
    }
    __syncthreads();
    if (tid < DD) {
      const int h = tid >> 4, dh = tid & 15;
      const float denom = s_wsum[h] + s_wsum[h + 8];
      s_heads[tid] = (s_hp[h][dh] + s_hp[h + 8][dh]) / denom;
    }
    __syncthreads();

    // ---- E: glimpse = heads @ Wout
    {
      const int d = tid & 127, c = tid >> 7;
      float a = 0.f;
      const int k0 = c * 16;
#pragma unroll
      for (int k = k0; k < k0 + 16; ++k) a += s_heads[k] * Wout[k * DD + d];
      s_part[c][d] = a;
    }
    __syncthreads();
    if (tid < DD) {
      float a = 0.f;
#pragma unroll
      for (int c2 = 0; c2 < 8; ++c2) a += s_part[c2][tid];
      s_glimpse[tid] = a;
    }
    __syncthreads();

    // ---- F: logits[n] = 10*tanh(glimpse . logit_K[n] / sqrt(D)), masked
    {
      const int n = tid >> 1, half = tid & 1;
      const float4* lp =
          (const float4*)(projb + (size_t)n * D3 + 2 * DD + half * 64);
      float acc = 0.f;
#pragma unroll
      for (int v4 = 0; v4 < 16; ++v4) {
        float4 kv = lp[v4];
        const int d0 = half * 64 + v4 * 4;
        acc += s_glimpse[d0] * kv.x + s_glimpse[d0 + 1] * kv.y +
               s_glimpse[d0 + 2] * kv.z + s_glimpse[d0 + 3] * kv.w;
      }
      acc += __shfl_xor(acc, 1);
      if (half == 0) {
        float lg = 10.0f * tanhf(acc * inv_sqrt_d);
        if (s_visited[n]) lg = NEGV;
        s_logits[n] = lg;
      }
    }
    __syncthreads();

    // ---- G: argmax (first-index tie-break) + logZ
    if (wave < 8) {
      const int n = wave * 64 + lane;
      float v = s_logits[n];
      int idx = n;
#pragma unroll
      for (int off = 32; off >= 1; off >>= 1) {
        float ov = __shfl_xor(v, off);
        int oi = __shfl_xor(idx, off);
        if (ov > v || (ov == v && oi < idx)) { v = ov; idx = oi; }
      }
      if (lane == 0) { s_rm[wave] = v; s_ri[wave] = idx; }
    }
    __syncthreads();
    if (tid == 0) {
      float bv = s_rm[0];
      int bi = s_ri[0];
      for (int w2 = 1; w2 < 8; ++w2) {
        if (s_rm[w2] > bv || (s_rm[w2] == bv && s_ri[w2] < bi)) {
          bv = s_rm[w2];
          bi = s_ri[w2];
        }
      }
      s_m = bv;
      s_sel = bi;
    }
    __syncthreads();
    if (wave < 8) {
      const int n = wave * 64 + lane;
      float e = expf(s_logits[n] - s_m);
#pragma unroll
      for (int off = 32; off >= 1; off >>= 1) e += __shfl_xor(e, off);
      if (lane == 0) s_es[wave] = e;
    }
    __syncthreads();
    if (tid == 0) {
      float S = 0.f;
      for (int w2 = 0; w2 < 8; ++w2) S += s_es[w2];
      s_logZ = s_m + logf(S);
    }
    __syncthreads();

    // ---- H: emit log_p row, pi; update state
    {
      const float lz = s_logZ;
      if (tid < NN) outp[(size_t)i * NN + tid] = s_logits[tid] - lz;
    }
    if (tid == 0) {
      const int sel = s_sel;
      s_ll += s_logits[sel] - s_logZ;
      s_visited[sel] = 1;
      if (i == 0) s_first = sel;
      s_prev = sel;
      out[PI_OFF + (size_t)b * NN + i] = (float)sel;
    }
    __syncthreads();
  }
  if (tid == 0) out[LL_OFF + b] = s_ll;
}

extern "C" void kernel_launch(void* const* d_in, const int* in_sizes, int n_in,
                              void* d_out, int out_size, void* d_ws,
                              size_t ws_size, hipStream_t stream) {
  const float* emb = (const float*)d_in[0];    // [B,N,D]
  const float* Wnp = (const float*)d_in[1];    // [D,3D]
  const float* Wf = (const float*)d_in[2];     // [D,D]
  const float* Wstep = (const float*)d_in[3];  // [2D,D]
  const float* Wout = (const float*)d_in[4];   // [D,D]
  const float* Wph = (const float*)d_in[5];    // [2D]
  float* out = (float*)d_out;

  float* proj = (float*)d_ws;                               // [B,N,3D] fp32
  float* fixedc = proj + (size_t)BATCH * NN * D3;           // [B,D]

  k_fixed<<<BATCH, 256, 0, stream>>>(emb, Wf, fixedc);
  k_proj<<<(BATCH * NN) / 32, 384, 0, stream>>>(emb, Wnp, proj);
  k_decode<<<BATCH, 1024, 0, stream>>>(emb, proj, fixedc, Wstep, Wout, Wph,
                                       out);
}

// Round 2
// 8516.956 us; speedup vs baseline: 2.1233x; 2.1233x over previous
//
#include <hip/hip_runtime.h>
#include <hip/hip_bf16.h>
#include <math.h>

#define BATCH 128
#define NN 512
#define DD 128
#define D3 384
#define NEGV (-1.0e9f)
#define NEGINF (-1.0e30f)

// ---- k_fixed: graph mean -> fixed ctx; also q0 = fixed + Wph @ Wstep --------
__global__ __launch_bounds__(256) void k_fixed(const float* __restrict__ emb,
                                               const float* __restrict__ Wf,
                                               const float* __restrict__ Wstep,
                                               const float* __restrict__ Wph,
                                               float* __restrict__ fixedc,
                                               float* __restrict__ q0) {
  const int b = blockIdx.x;
  __shared__ float s_part[2][DD];
  __shared__ float s_ge[DD];
  const int tid = threadIdx.x;
  const int d = tid & 127, c = tid >> 7;
  const float* e = emb + (size_t)b * NN * DD;
  float acc = 0.f;
  for (int n = c * 256; n < c * 256 + 256; ++n) acc += e[(size_t)n * DD + d];
  s_part[c][d] = acc;
  __syncthreads();
  if (tid < DD) s_ge[tid] = (s_part[0][tid] + s_part[1][tid]) * (1.0f / 512.0f);
  __syncthreads();
  if (tid < DD) {
    float a = 0.f;
    for (int k = 0; k < DD; ++k) a += s_ge[k] * Wf[k * DD + tid];
    fixedc[b * DD + tid] = a;
    float pq = 0.f;
    for (int k = 0; k < 2 * DD; ++k) pq += Wph[k] * Wstep[k * DD + tid];
    q0[b * DD + tid] = a + pq;
  }
}

// ---- proj = emb @ W_node_proj : [B*N,128] x [128,384] -----------------------
__global__ __launch_bounds__(384) void k_proj(const float* __restrict__ emb,
                                              const float* __restrict__ Wp,
                                              float* __restrict__ proj) {
  const size_t row0 = (size_t)blockIdx.x * 32;
  __shared__ float s_A[32][DD];
  const int tid = threadIdx.x;  // 384
  for (int t = tid; t < 32 * DD; t += 384)
    s_A[t >> 7][t & 127] = emb[row0 * DD + t];
  __syncthreads();
  float acc[32];
#pragma unroll
  for (int r = 0; r < 32; ++r) acc[r] = 0.f;
  const int c = tid;
  for (int k = 0; k < DD; ++k) {
    float w = Wp[k * D3 + c];
#pragma unroll
    for (int r = 0; r < 32; ++r) acc[r] += s_A[r][k] * w;
  }
  for (int r = 0; r < 32; ++r) proj[(row0 + r) * D3 + c] = acc[r];
}

// ---- E12 = emb @ Wstep (E1 = cols 0:128 vs W1, E2 = cols 128:256 vs W2) -----
__global__ __launch_bounds__(256) void k_ectx(const float* __restrict__ emb,
                                              const float* __restrict__ Wstep,
                                              float* __restrict__ E12) {
  const size_t row0 = (size_t)blockIdx.x * 32;
  __shared__ float s_A[32][DD];
  const int tid = threadIdx.x;  // 256
  for (int t = tid; t < 32 * DD; t += 256)
    s_A[t >> 7][t & 127] = emb[row0 * DD + t];
  __syncthreads();
  float acc[32];
#pragma unroll
  for (int r = 0; r < 32; ++r) acc[r] = 0.f;
  const int c = tid;
  const float* wp = (c < DD) ? (Wstep + c) : (Wstep + DD * DD + (c - DD));
  for (int k = 0; k < DD; ++k) {
    float w = wp[(size_t)k * DD];
#pragma unroll
    for (int r = 0; r < 32; ++r) acc[r] += s_A[r][k] * w;
  }
  for (int r = 0; r < 32; ++r) E12[(row0 + r) * 256 + c] = acc[r];
}

// ---- persistent greedy decode: one block per batch --------------------------
__global__ __launch_bounds__(1024) void k_decode(
    const float* __restrict__ emb, const float* __restrict__ proj,
    const float* __restrict__ fixedc, const float* __restrict__ q0,
    const float* __restrict__ E12, const float* __restrict__ Wstep,
    const float* __restrict__ Wout, const float* __restrict__ Wph,
    const int useE, float* __restrict__ out) {
  const int b = blockIdx.x;
  const int tid = threadIdx.x;
  const int lane = tid & 63;
  const int wave = tid >> 6;

  __shared__ int s_idx[NN];
  __shared__ int s_pos[NN];
  __shared__ unsigned char s_visited[NN];
  __shared__ float s_q[DD];
  __shared__ float s_red[16][8];
  __shared__ float s_mh[8];
  __shared__ float s_hacc[16][8][17];
  __shared__ float s_part[8][DD];
  __shared__ float s_heads[DD];
  __shared__ float s_glimpse[DD];
  __shared__ float s_logits[NN];
  __shared__ float s_rm[8];
  __shared__ int s_ri[8];
  __shared__ float s_es[8];
  __shared__ float s_ctx[2 * DD];  // fallback path only
  __shared__ int s_sel, s_first, s_prev, s_M;
  __shared__ float s_m, s_logZ, s_ll;

  const float inv_sqrt_d = 0.08838834764831845f;  // 1/sqrt(128)
  const size_t eb = (size_t)b * NN * DD;
  const size_t e2 = (size_t)b * NN * 256;
  const float* projb = proj + (size_t)b * NN * D3;
  float* outp = out + (size_t)b * NN * NN;
  const size_t PI_OFF = (size_t)BATCH * NN * NN;
  const size_t LL_OFF = PI_OFF + (size_t)BATCH * NN;

  // persistent per-thread Wout fragment: thread (c=tid>>7,d=tid&127) holds
  // Wout[c*16+k][d], k=0..15
  const int wc = tid >> 7, wd = tid & 127;
  float Wout_reg[16];
#pragma unroll
  for (int k = 0; k < 16; ++k) Wout_reg[k] = Wout[(wc * 16 + k) * DD + wd];
  const float f_reg = (tid < DD) ? fixedc[b * DD + tid] : 0.f;

  if (tid < NN) {
    s_idx[tid] = tid;
    s_pos[tid] = tid;
    s_visited[tid] = 0;
  }
  if (tid == 0) { s_first = 0; s_prev = 0; s_ll = 0.f; s_M = NN; }
  __syncthreads();

  for (int i = 0; i < NN; ++i) {
    const int M = s_M;

    // ---- Q: q = fixed + E1[first] + E2[prev]  (or q0 at i==0)
    if (useE) {
      if (tid < DD) {
        float q;
        if (i == 0)
          q = q0[b * DD + tid];
        else
          q = f_reg + E12[e2 + (size_t)s_first * 256 + tid] +
              E12[e2 + (size_t)s_prev * 256 + DD + tid];
        s_q[tid] = q;
      }
      __syncthreads();
    } else {
      // fallback: assemble ctx, GEMV against Wstep
      if (tid < 2 * DD) {
        float v;
        if (i == 0)
          v = Wph[tid];
        else
          v = (tid < DD) ? emb[eb + (size_t)s_first * DD + tid]
                         : emb[eb + (size_t)s_prev * DD + (tid - DD)];
        s_ctx[tid] = v;
      }
      __syncthreads();
      {
        const int d = tid & 127, c = tid >> 7;
        float a = 0.f;
        const int k0 = c * 32;
        for (int k = k0; k < k0 + 32; ++k) a += s_ctx[k] * Wstep[k * DD + d];
        s_part[c][d] = a;
      }
      __syncthreads();
      if (tid < DD) {
        float a = f_reg;
#pragma unroll
        for (int c2 = 0; c2 < 8; ++c2) a += s_part[c2][tid];
        s_q[tid] = a;
      }
      __syncthreads();
    }

    // ---- C: compat over compacted rows, per-head max
    const int h = tid & 7, r = tid >> 3;  // r in 0..127
    float qf[16];
#pragma unroll
    for (int d = 0; d < 16; ++d) qf[d] = s_q[h * 16 + d];
    float cc[4];
    int nn[4];
    float mloc = NEGINF;
#pragma unroll
    for (int k = 0; k < 4; ++k) {
      const int j = r + k * 128;
      float cv = NEGINF;
      int n = 0;
      if (j < M) {
        n = s_idx[j];
        const float4* kp = (const float4*)(projb + (size_t)n * D3 + h * 16);
        float4 a0 = kp[0], a1 = kp[1], a2 = kp[2], a3 = kp[3];
        float acc = qf[0] * a0.x + qf[1] * a0.y + qf[2] * a0.z + qf[3] * a0.w +
                    qf[4] * a1.x + qf[5] * a1.y + qf[6] * a1.z + qf[7] * a1.w +
                    qf[8] * a2.x + qf[9] * a2.y + qf[10] * a2.z + qf[11] * a2.w +
                    qf[12] * a3.x + qf[13] * a3.y + qf[14] * a3.z + qf[15] * a3.w;
        cv = acc * 0.25f;  // 1/sqrt(16)
      }
      cc[k] = cv;
      nn[k] = n;
      mloc = fmaxf(mloc, cv);
    }
#pragma unroll
    for (int off = 8; off <= 32; off <<= 1) mloc = fmaxf(mloc, __shfl_xor(mloc, off));
    if (lane < 8) s_red[wave][lane] = mloc;
    __syncthreads();
    if (tid < 8) {
      float m = NEGINF;
#pragma unroll
      for (int w = 0; w < 16; ++w) m = fmaxf(m, s_red[w][tid]);
      s_mh[tid] = m;
    }
    __syncthreads();

    // ---- D: p = exp(c-m), weighted gV accumulation, hierarchical reduce
    {
      const float mh = s_mh[h];
      float ssum = 0.f;
      float acc[16];
#pragma unroll
      for (int d = 0; d < 16; ++d) acc[d] = 0.f;
#pragma unroll
      for (int k = 0; k < 4; ++k) {
        if (r + k * 128 < M) {
          const float p = expf(cc[k] - mh);
          ssum += p;
          const float4* vp =
              (const float4*)(projb + (size_t)nn[k] * D3 + DD + h * 16);
          float4 v0 = vp[0], v1 = vp[1], v2 = vp[2], v3 = vp[3];
          acc[0] += p * v0.x;  acc[1] += p * v0.y;
          acc[2] += p * v0.z;  acc[3] += p * v0.w;
          acc[4] += p * v1.x;  acc[5] += p * v1.y;
          acc[6] += p * v1.z;  acc[7] += p * v1.w;
          acc[8] += p * v2.x;  acc[9] += p * v2.y;
          acc[10] += p * v2.z; acc[11] += p * v2.w;
          acc[12] += p * v3.x; acc[13] += p * v3.y;
          acc[14] += p * v3.z; acc[15] += p * v3.w;
        }
      }
#pragma unroll
      for (int off = 8; off <= 32; off <<= 1) {
        ssum += __shfl_xor(ssum, off);
#pragma unroll
        for (int d = 0; d < 16; ++d) acc[d] += __shfl_xor(acc[d], off);
      }
      if (lane < 8) {
        s_hacc[wave][lane][16] = ssum;
#pragma unroll
        for (int d = 0; d < 16; ++d) s_hacc[wave][lane][d] = acc[d];
      }
    }
    __syncthreads();
    if (tid < DD) {
      const int hh = tid >> 4, dh = tid & 15;
      float a = 0.f, s = 0.f;
#pragma unroll
      for (int w = 0; w < 16; ++w) {
        a += s_hacc[w][hh][dh];
        s += s_hacc[w][hh][16];
      }
      s_heads[tid] = a / s;
    }
    __syncthreads();

    // ---- E: glimpse = heads @ Wout (Wout in registers)
    {
      float a = 0.f;
#pragma unroll
      for (int k = 0; k < 16; ++k) a += s_heads[wc * 16 + k] * Wout_reg[k];
      s_part[wc][wd] = a;
    }
    __syncthreads();
    if (tid < DD) {
      float a = 0.f;
#pragma unroll
      for (int c2 = 0; c2 < 8; ++c2) a += s_part[c2][tid];
      s_glimpse[tid] = a;
    }
    __syncthreads();

    // ---- F: logits over compacted rows; visited get NEGV
    if (tid < NN && s_visited[tid]) s_logits[tid] = NEGV;
    {
      const int jj = tid >> 1, half = tid & 1;
      if (jj < M) {
        const int n = s_idx[jj];
        const float4* lp =
            (const float4*)(projb + (size_t)n * D3 + 2 * DD + half * 64);
        float a = 0.f;
#pragma unroll
        for (int v4 = 0; v4 < 16; ++v4) {
          float4 kv = lp[v4];
          const int d0 = half * 64 + v4 * 4;
          a += s_glimpse[d0] * kv.x + s_glimpse[d0 + 1] * kv.y +
               s_glimpse[d0 + 2] * kv.z + s_glimpse[d0 + 3] * kv.w;
        }
        a += __shfl_xor(a, 1);
        if (half == 0) s_logits[n] = 10.0f * tanhf(a * inv_sqrt_d);
      }
    }
    __syncthreads();

    // ---- G: argmax (first-index tie-break) + logZ
    if (wave < 8) {
      const int n = wave * 64 + lane;
      float v = s_logits[n];
      int idx = n;
#pragma unroll
      for (int off = 32; off >= 1; off >>= 1) {
        float ov = __shfl_xor(v, off);
        int oi = __shfl_xor(idx, off);
        if (ov > v || (ov == v && oi < idx)) { v = ov; idx = oi; }
      }
      if (lane == 0) { s_rm[wave] = v; s_ri[wave] = idx; }
    }
    __syncthreads();
    if (tid == 0) {
      float bv = s_rm[0];
      int bi = s_ri[0];
      for (int w2 = 1; w2 < 8; ++w2) {
        if (s_rm[w2] > bv || (s_rm[w2] == bv && s_ri[w2] < bi)) {
          bv = s_rm[w2];
          bi = s_ri[w2];
        }
      }
      s_m = bv;
      s_sel = bi;
    }
    __syncthreads();
    if (wave < 8) {
      const int n = wave * 64 + lane;
      float e = expf(s_logits[n] - s_m);
#pragma unroll
      for (int off = 32; off >= 1; off >>= 1) e += __shfl_xor(e, off);
      if (lane == 0) s_es[wave] = e;
    }
    __syncthreads();
    if (tid == 0) {
      float S = 0.f;
      for (int w2 = 0; w2 < 8; ++w2) S += s_es[w2];
      s_logZ = s_m + logf(S);
    }
    __syncthreads();

    // ---- H: emit log_p row, pi; update state + compact removal
    {
      const float lz = s_logZ;
      if (tid < NN) outp[(size_t)i * NN + tid] = s_logits[tid] - lz;
      if (tid == 0) {
        const int sel = s_sel;
        s_ll += s_logits[sel] - lz;
        s_visited[sel] = 1;
        if (i == 0) s_first = sel;
        s_prev = sel;
        out[PI_OFF + (size_t)b * NN + i] = (float)sel;
        const int p = s_pos[sel];
        const int last = s_idx[M - 1];
        s_idx[p] = last;
        s_pos[last] = p;
        s_M = M - 1;
      }
    }
    __syncthreads();
  }
  if (tid == 0) out[LL_OFF + b] = s_ll;
}

extern "C" void kernel_launch(void* const* d_in, const int* in_sizes, int n_in,
                              void* d_out, int out_size, void* d_ws,
                              size_t ws_size, hipStream_t stream) {
  const float* emb = (const float*)d_in[0];    // [B,N,D]
  const float* Wnp = (const float*)d_in[1];    // [D,3D]
  const float* Wf = (const float*)d_in[2];     // [D,D]
  const float* Wstep = (const float*)d_in[3];  // [2D,D]
  const float* Wout = (const float*)d_in[4];   // [D,D]
  const float* Wph = (const float*)d_in[5];    // [2D]
  float* out = (float*)d_out;

  const size_t projN = (size_t)BATCH * NN * D3;
  const size_t eN = (size_t)BATCH * NN * 256;
  const size_t need_full = (projN + eN + 2 * (size_t)BATCH * DD) * 4;

  float* proj = (float*)d_ws;
  float* E12 = proj + projN;
  const int useE = (ws_size >= need_full) ? 1 : 0;
  float* fixedc = useE ? (E12 + eN) : (proj + projN);
  float* q0 = fixedc + (size_t)BATCH * DD;

  k_fixed<<<BATCH, 256, 0, stream>>>(emb, Wf, Wstep, Wph, fixedc, q0);
  k_proj<<<(BATCH * NN) / 32, 384, 0, stream>>>(emb, Wnp, proj);
  if (useE) k_ectx<<<(BATCH * NN) / 32, 256, 0, stream>>>(emb, Wstep, E12);
  k_decode<<<BATCH, 1024, 0, stream>>>(emb, proj, fixedc, q0,
                                       useE ? E12 : nullptr, Wstep, Wout, Wph,
                                       useE, out);
}